// Round 6
// baseline (1525.695 us; speedup 1.0000x reference)
//
#include <hip/hip_runtime.h>
#include <hip/hip_cooperative_groups.h>
#include <math.h>

namespace cg = cooperative_groups;

#define D_ 256
#define NL_ 4
#define NC_ 2
#define L_LEN 1024
#define NSTATE_ 64
#define DIN_ 512
#define H_ 8
#define P_ 64
#define CONVDIM_ 640
#define DPROJ_ 1160
#define EPS_ 1e-5f
#define NCH_ 16
#define NBLK 256
#define NTHR 512

__device__ __forceinline__ float siluf(float x) { return x / (1.f + expf(-x)); }
__device__ __forceinline__ float geluf(float x) { return 0.5f * x * (1.f + erff(x * 0.70710678118654752f)); }

__global__ void __launch_bounds__(NTHR, 2) mega(
        const int* __restrict__ ids, const float* __restrict__ emb,
        const float* __restrict__ pos, const float* __restrict__ Wins,
        const float* __restrict__ cw, const float* __restrict__ cb,
        const float* __restrict__ dtb, const float* __restrict__ Alog,
        const float* __restrict__ Dpar, const float* __restrict__ nw,
        const float* __restrict__ Wout, const float* __restrict__ pw,
        const float* __restrict__ pb, const float* __restrict__ c1w,
        const float* __restrict__ c1b, const float* __restrict__ c2w,
        const float* __restrict__ c2b, float* __restrict__ out,
        float* __restrict__ x, float* __restrict__ zx, float* __restrict__ y,
        float* __restrict__ Sbuf, float* __restrict__ Ctil,
        float* __restrict__ decay, float* __restrict__ pooled,
        float* __restrict__ psum, float* __restrict__ pmax) {
    cg::grid_group grid = cg::this_grid();
    __shared__ float smem[12672];   // 50.7 KB, shared by all phases
    const int blk = blockIdx.x, tid = threadIdx.x;

    // ================= embed =================
    for (int i = blk * NTHR + tid; i < 524288; i += NBLK * NTHR) {
        int d = i & 255, bl = i >> 8, l = bl & 1023;
        x[i] = emb[ids[bl] * D_ + d] + pos[l * D_ + d];
    }
    grid.sync();

    for (int layer = 0; layer < NL_; ++layer) {
        const float* Win = Wins + (size_t)layer * DPROJ_ * D_;
        const float* cwl = cw + (size_t)layer * CONVDIM_ * 4;
        const float* cbl = cb + (size_t)layer * CONVDIM_;
        const float* dtbl = dtb + layer * H_;
        const float* All = Alog + layer * H_;
        const float* Dpl = Dpar + layer * H_;
        const float* nwl = nw + (size_t)layer * DIN_;
        const float* Wol = Wout + (size_t)layer * D_ * DIN_;

        // ======== in-proj GEMM: zx[2048,1160] = x[2048,256] @ Win^T ========
        {
            float* As = smem;            // [16][132]
            float* Bs = smem + 2112;     // [16][68]
            const int arow = tid >> 2, akq = (tid & 3) * 4;
            const int tm = tid >> 4, tn = tid & 15;
            for (int t = blk; t < 304; t += NBLK) {
                const int rowt = t & 15, colt = t >> 4;   // 16 x 19
                const int row0 = rowt * 128, col0 = colt * 64;
                const bool bact = tid < 256;
                const int bcol = col0 + (tid >> 2);
                const bool bok = bact && bcol < DPROJ_;
                const float* aptr = x + (size_t)(row0 + arow) * D_ + akq;
                float4 pa = *(const float4*)aptr;
                float4 pbv = bok ? *(const float4*)&Win[(size_t)bcol * D_ + akq]
                                 : float4{0.f, 0.f, 0.f, 0.f};
                float acc[4][4] = {};
                for (int k0 = 0; k0 < D_; k0 += 16) {
                    __syncthreads();
                    As[(akq + 0) * 132 + arow] = pa.x;
                    As[(akq + 1) * 132 + arow] = pa.y;
                    As[(akq + 2) * 132 + arow] = pa.z;
                    As[(akq + 3) * 132 + arow] = pa.w;
                    if (bact) {
                        int br = tid >> 2;
                        Bs[(akq + 0) * 68 + br] = pbv.x;
                        Bs[(akq + 1) * 68 + br] = pbv.y;
                        Bs[(akq + 2) * 68 + br] = pbv.z;
                        Bs[(akq + 3) * 68 + br] = pbv.w;
                    }
                    __syncthreads();
                    if (k0 + 16 < D_) {
                        pa = *(const float4*)(aptr + k0 + 16);
                        if (bok) pbv = *(const float4*)&Win[(size_t)bcol * D_ + k0 + 16 + akq];
                    }
#pragma unroll
                    for (int kk = 0; kk < 16; ++kk) {
                        float a[4], b[4];
#pragma unroll
                        for (int i = 0; i < 4; ++i) a[i] = As[kk * 132 + tm * 4 + i];
#pragma unroll
                        for (int j = 0; j < 4; ++j) b[j] = Bs[kk * 68 + tn * 4 + j];
#pragma unroll
                        for (int i = 0; i < 4; ++i)
#pragma unroll
                            for (int j = 0; j < 4; ++j) acc[i][j] += a[i] * b[j];
                    }
                }
                int cbase = col0 + tn * 4;
#pragma unroll
                for (int i = 0; i < 4; ++i) {
                    size_t r = (size_t)(row0 + tm * 4 + i) * DPROJ_ + cbase;
                    if (cbase + 3 < DPROJ_) {
                        float4 v = {acc[i][0], acc[i][1], acc[i][2], acc[i][3]};
                        *(float4*)&zx[r] = v;
                    } else {
#pragma unroll
                        for (int j = 0; j < 4; ++j)
                            if (cbase + j < DPROJ_) zx[r + j] = acc[i][j];
                    }
                }
                __syncthreads();
            }
        }
        grid.sync();

        // ======== fused SSM (conv+dt+S_local+decay+Ctil+G+intra-Y) ========
        {
            float (*U)[65] = (float(*)[65])smem;
            float (*V)[65] = (float(*)[65])(smem + 4160);
            float (*W)[65] = (float(*)[65])(smem + 8320);
            float* sdt = smem + 12480;
            float* cs = smem + 12544;
            float* wj = smem + 12608;
            const int bh = blk >> 4, c = blk & 15;
            const int b = bh >> 3, h = bh & 7;
            const int l0 = c << 6;
            const int wid8 = tid >> 6, lane = tid & 63;

            const int chx = h * P_ + lane;
            const int chb = DIN_ + lane;
            const int chc = DIN_ + NSTATE_ + lane;
            float wx0 = cwl[chx * 4], wx1 = cwl[chx * 4 + 1], wx2 = cwl[chx * 4 + 2], wx3 = cwl[chx * 4 + 3];
            float wb0 = cwl[chb * 4], wb1 = cwl[chb * 4 + 1], wb2 = cwl[chb * 4 + 2], wb3 = cwl[chb * 4 + 3];
            float wc0 = cwl[chc * 4], wc1 = cwl[chc * 4 + 1], wc2 = cwl[chc * 4 + 2], wc3 = cwl[chc * 4 + 3];
            float bx = cbl[chx], bb = cbl[chb], bc = cbl[chc];
            for (int r = 0; r < 64; r += 8) {
                int j = r + wid8;
                int l = l0 + j;
                float ax = bx, ab = bb, ac = bc;
#pragma unroll
                for (int k = 0; k < 4; ++k) {
                    int t = l - 3 + k;
                    if (t >= 0) {
                        const float* row = zx + (size_t)(b * L_LEN + t) * DPROJ_;
                        float wxk = (k == 0) ? wx0 : (k == 1) ? wx1 : (k == 2) ? wx2 : wx3;
                        float wbk = (k == 0) ? wb0 : (k == 1) ? wb1 : (k == 2) ? wb2 : wb3;
                        float wck = (k == 0) ? wc0 : (k == 1) ? wc1 : (k == 2) ? wc2 : wc3;
                        ax += wxk * row[DIN_ + chx];
                        ab += wbk * row[DIN_ + chb];
                        ac += wck * row[DIN_ + chc];
                    }
                }
                U[j][lane] = siluf(ax);
                V[j][lane] = siluf(ab);
                W[j][lane] = siluf(ac);
            }
            if (tid < 64) {
                float xv = zx[(size_t)(b * L_LEN + l0 + tid) * DPROJ_ + (DPROJ_ - H_) + h] + dtbl[h];
                float sp = fmaxf(xv, 0.f) + log1pf(expf(-fabsf(xv)));
                sdt[tid] = sp;
                cs[tid] = sp * (-expf(All[h]));
            }
            __syncthreads();
            if (tid == 0) {
                float s = 0.f;
                for (int j = 0; j < 64; ++j) { s += cs[j]; cs[j] = s; }
            }
            __syncthreads();
            if (tid < 64) wj[tid] = expf(cs[63] - cs[tid]) * sdt[tid];
            if (tid == 0) decay[bh * NCH_ + c] = expf(cs[63]);
            __syncthreads();

            const size_t sbase = (size_t)(bh * NCH_ + c) * 4096;
            const int t4 = (tid & 15) * 4, r4 = ((tid >> 4) & 15) * 4;
            // S_local (256 threads, 4x4)
            if (tid < 256) {
                float acc[4][4] = {};
                for (int j = 0; j < 64; ++j) {
                    float w = wj[j];
                    float4 xv = *(const float4*)&U[j][r4];
                    float4 bv = *(const float4*)&V[j][t4];
                    float xw[4] = {xv.x * w, xv.y * w, xv.z * w, xv.w * w};
#pragma unroll
                    for (int ii = 0; ii < 4; ++ii) {
                        acc[ii][0] += xw[ii] * bv.x;
                        acc[ii][1] += xw[ii] * bv.y;
                        acc[ii][2] += xw[ii] * bv.z;
                        acc[ii][3] += xw[ii] * bv.w;
                    }
                }
#pragma unroll
                for (int ii = 0; ii < 4; ++ii) {
                    float4 v = {acc[ii][0], acc[ii][1], acc[ii][2], acc[ii][3]};
                    *(float4*)&Sbuf[sbase + (size_t)(r4 + ii) * 64 + t4] = v;
                }
            }
            // Ctil (512 threads)
            for (int r = 0; r < 64; r += 8) {
                int j = r + wid8;
                Ctil[sbase + j * 64 + lane] = expf(cs[j]) * W[j][lane];
            }
            // G + masked transpose (256 threads)
            float wt[4][4];
            if (tid < 256) {
                float g[4][4] = {};
                for (int ng = 0; ng < 64; ng += 4) {
                    float4 cf[4], bf[4];
#pragma unroll
                    for (int ii = 0; ii < 4; ++ii) cf[ii] = *(const float4*)&W[r4 + ii][ng];
#pragma unroll
                    for (int jj = 0; jj < 4; ++jj) bf[jj] = *(const float4*)&V[t4 + jj][ng];
#pragma unroll
                    for (int ii = 0; ii < 4; ++ii)
#pragma unroll
                        for (int jj = 0; jj < 4; ++jj)
                            g[ii][jj] += cf[ii].x * bf[jj].x + cf[ii].y * bf[jj].y +
                                         cf[ii].z * bf[jj].z + cf[ii].w * bf[jj].w;
                }
#pragma unroll
                for (int ii = 0; ii < 4; ++ii) {
                    int i = r4 + ii;
                    float csi = cs[i];
#pragma unroll
                    for (int jj = 0; jj < 4; ++jj) {
                        int j = t4 + jj;
                        wt[ii][jj] = (j <= i) ? expf(fminf(csi - cs[j], 0.f)) * sdt[j] * g[ii][jj] : 0.f;
                    }
                }
            }
            __syncthreads();
            if (tid < 256) {
#pragma unroll
                for (int jj = 0; jj < 4; ++jj) {
                    float4 v = {wt[0][jj], wt[1][jj], wt[2][jj], wt[3][jj]};
                    *(float4*)&V[t4 + jj][r4] = v;
                }
            }
            __syncthreads();
            // intra Y (256 threads)
            if (tid < 256) {
                float acc[4][4] = {};
                for (int j = 0; j < 64; ++j) {
                    float4 wv = *(const float4*)&V[j][r4];
                    float4 xv = *(const float4*)&U[j][t4];
                    float ws[4] = {wv.x, wv.y, wv.z, wv.w};
#pragma unroll
                    for (int ii = 0; ii < 4; ++ii) {
                        acc[ii][0] += ws[ii] * xv.x;
                        acc[ii][1] += ws[ii] * xv.y;
                        acc[ii][2] += ws[ii] * xv.z;
                        acc[ii][3] += ws[ii] * xv.w;
                    }
                }
                float Dh = Dpl[h];
#pragma unroll
                for (int ii = 0; ii < 4; ++ii) {
                    float4 xv = *(const float4*)&U[r4 + ii][t4];
                    float4 v = {acc[ii][0] + Dh * xv.x, acc[ii][1] + Dh * xv.y,
                                acc[ii][2] + Dh * xv.z, acc[ii][3] + Dh * xv.w};
                    *(float4*)&y[(size_t)(b * L_LEN + l0 + r4 + ii) * DIN_ + h * P_ + t4] = v;
                }
            }
        }
        grid.sync();

        // ======== cross-chunk scan (65536 element-threads) ========
        {
            int gtid = blk * NTHR + tid;
            if (gtid < 65536) {
                int bh = gtid >> 12, e = gtid & 4095;
                size_t base = (size_t)bh * 65536 + e;
                float dec[16], tmp[16];
#pragma unroll
                for (int c2 = 0; c2 < 16; ++c2) dec[c2] = decay[bh * 16 + c2];
#pragma unroll
                for (int c2 = 0; c2 < 16; ++c2) tmp[c2] = Sbuf[base + (c2 << 12)];
                float run = 0.f;
#pragma unroll
                for (int c2 = 0; c2 < 16; ++c2) {
                    Sbuf[base + (c2 << 12)] = run;
                    run = dec[c2] * run + tmp[c2];
                }
            }
        }
        grid.sync();

        // ======== inter-chunk: y += Ctil · S_in ========
        {
            float (*Sm)[65] = (float(*)[65])smem;
            float (*Cm)[65] = (float(*)[65])(smem + 4160);
            const int bh = blk >> 4, c = blk & 15;
            const int b = bh >> 3, h = bh & 7;
            const int l0 = c << 6;
            const int wid8 = tid >> 6, lane = tid & 63;
            const size_t base = (size_t)(bh * NCH_ + c) * 4096;
            for (int r = 0; r < 64; r += 8) {
                int pp = r + wid8;
                Sm[pp][lane] = Sbuf[base + pp * 64 + lane];
                Cm[pp][lane] = Ctil[base + pp * 64 + lane];
            }
            __syncthreads();
            if (tid < 256) {
                const int t4 = (tid & 15) * 4, r4 = (tid >> 4) * 4;
                float acc[4][4] = {};
                for (int ng = 0; ng < 64; ng += 4) {
                    float4 cf[4], sf[4];
#pragma unroll
                    for (int ii = 0; ii < 4; ++ii) cf[ii] = *(const float4*)&Cm[r4 + ii][ng];
#pragma unroll
                    for (int pp = 0; pp < 4; ++pp) sf[pp] = *(const float4*)&Sm[t4 + pp][ng];
#pragma unroll
                    for (int ii = 0; ii < 4; ++ii)
#pragma unroll
                        for (int pp = 0; pp < 4; ++pp)
                            acc[ii][pp] += cf[ii].x * sf[pp].x + cf[ii].y * sf[pp].y +
                                           cf[ii].z * sf[pp].z + cf[ii].w * sf[pp].w;
                }
#pragma unroll
                for (int ii = 0; ii < 4; ++ii) {
                    float* dst = &y[(size_t)(b * L_LEN + l0 + r4 + ii) * DIN_ + h * P_ + t4];
                    float4 v = *(const float4*)dst;
                    v.x += acc[ii][0]; v.y += acc[ii][1]; v.z += acc[ii][2]; v.w += acc[ii][3];
                    *(float4*)dst = v;
                }
            }
        }
        grid.sync();

        // ======== gated RMSNorm (8 rows per block, 2 at a time) ========
        {
            float* sred = smem;
            const int grp = tid >> 8, t = tid & 255;
            for (int it = 0; it < 4; ++it) {
                int row = blk * 8 + it * 2 + grp;
                float* yr = y + (size_t)row * DIN_;
                const float* zr = zx + (size_t)row * DPROJ_;
                float g0 = yr[t] * siluf(zr[t]);
                float g1 = yr[t + 256] * siluf(zr[t + 256]);
                float ss = g0 * g0 + g1 * g1;
#pragma unroll
                for (int o = 32; o; o >>= 1) ss += __shfl_xor(ss, o, 64);
                if ((t & 63) == 0) sred[grp * 4 + (t >> 6)] = ss;
                __syncthreads();
                float tot = sred[grp * 4] + sred[grp * 4 + 1] + sred[grp * 4 + 2] + sred[grp * 4 + 3];
                float scale = rsqrtf(tot * (1.f / DIN_) + EPS_);
                yr[t] = g0 * scale * nwl[t];
                yr[t + 256] = g1 * scale * nwl[t + 256];
                __syncthreads();
            }
        }
        grid.sync();

        // ======== out-proj GEMM (+residual): x += y @ Wol^T, split-K4 ========
        {
            float* As = smem;            // [16][132]
            float* Bs = smem + 2112;     // [16][68]
            const int tileid = blk >> 2, ks = blk & 3;
            const int row0 = (tileid >> 2) * 128, col0 = (tileid & 3) * 64;
            const int kbase = ks * 128;
            const int arow = tid >> 2, akq = (tid & 3) * 4;
            const int tm = tid >> 4, tn = tid & 15;
            const bool bact = tid < 256;
            const int bcol = col0 + (tid >> 2);
            const float* aptr = y + (size_t)(row0 + arow) * DIN_ + kbase + akq;
            float4 pa = *(const float4*)aptr;
            float4 pbv = bact ? *(const float4*)&Wol[(size_t)bcol * DIN_ + kbase + akq]
                              : float4{0.f, 0.f, 0.f, 0.f};
            float acc[4][4] = {};
            for (int k0 = 0; k0 < 128; k0 += 16) {
                __syncthreads();
                As[(akq + 0) * 132 + arow] = pa.x;
                As[(akq + 1) * 132 + arow] = pa.y;
                As[(akq + 2) * 132 + arow] = pa.z;
                As[(akq + 3) * 132 + arow] = pa.w;
                if (bact) {
                    int br = tid >> 2;
                    Bs[(akq + 0) * 68 + br] = pbv.x;
                    Bs[(akq + 1) * 68 + br] = pbv.y;
                    Bs[(akq + 2) * 68 + br] = pbv.z;
                    Bs[(akq + 3) * 68 + br] = pbv.w;
                }
                __syncthreads();
                if (k0 + 16 < 128) {
                    pa = *(const float4*)(aptr + k0 + 16);
                    if (bact) pbv = *(const float4*)&Wol[(size_t)bcol * DIN_ + kbase + k0 + 16 + akq];
                }
#pragma unroll
                for (int kk = 0; kk < 16; ++kk) {
                    float a[4], b[4];
#pragma unroll
                    for (int i = 0; i < 4; ++i) a[i] = As[kk * 132 + tm * 4 + i];
#pragma unroll
                    for (int j = 0; j < 4; ++j) b[j] = Bs[kk * 68 + tn * 4 + j];
#pragma unroll
                    for (int i = 0; i < 4; ++i)
#pragma unroll
                        for (int j = 0; j < 4; ++j) acc[i][j] += a[i] * b[j];
                }
            }
            int cbase = col0 + tn * 4;
#pragma unroll
            for (int i = 0; i < 4; ++i) {
                size_t r = (size_t)(row0 + tm * 4 + i) * D_ + cbase;
#pragma unroll
                for (int j = 0; j < 4; ++j) atomicAdd(&x[r + j], acc[i][j]);
            }
            __syncthreads();
        }
        grid.sync();
    }

    // ================= pooling =================
    if (blk < 32 && tid < 256) {
        int b = blk >> 4, ch = blk & 15, d = tid;
        const float* xb = x + ((size_t)(b * L_LEN) + ch * 64) * D_ + d;
        float s = 0.f, m = -INFINITY;
        for (int l = 0; l < 64; ++l) {
            float v = xb[(size_t)l * D_];
            s += v;
            m = fmaxf(m, v);
        }
        psum[(b * 16 + ch) * D_ + d] = s;
        pmax[(b * 16 + ch) * D_ + d] = m;
    }
    grid.sync();
    if (blk == 0) {
        int b = tid >> 8, d = tid & 255;
        float s = 0.f, m = -INFINITY;
        for (int ch = 0; ch < 16; ++ch) {
            s += psum[(b * 16 + ch) * D_ + d];
            m = fmaxf(m, pmax[(b * 16 + ch) * D_ + d]);
        }
        pooled[b * D_ + d] = (s * (1.f / L_LEN) + m) * 0.5f;
    }
    grid.sync();
    // ================= head =================
    if (blk < 2) {
        float* sp = smem;
        float* s1 = smem + 256;
        float* s2 = smem + 512;
        int b = blk;
        if (tid < 256) sp[tid] = pooled[b * D_ + tid];
        __syncthreads();
        if (tid < 256) {
            float acc = pb[tid];
            for (int d = 0; d < 256; ++d) acc += sp[d] * pw[tid * 256 + d];
            s1[tid] = geluf(acc);
        }
        __syncthreads();
        if (tid < 128) {
            float a = c1b[tid];
            for (int d = 0; d < 256; ++d) a += s1[d] * c1w[tid * 256 + d];
            s2[tid] = geluf(a);
        }
        __syncthreads();
        if (tid < 2) {
            float a = c2b[tid];
            for (int d = 0; d < 128; ++d) a += s2[d] * c2w[tid * 128 + d];
            out[b * NC_ + tid] = a;
        }
    }
}

extern "C" void kernel_launch(void* const* d_in, const int* in_sizes, int n_in,
                              void* d_out, int out_size, void* d_ws, size_t ws_size,
                              hipStream_t stream) {
    const int* ids    = (const int*)d_in[0];
    const float* emb  = (const float*)d_in[1];
    const float* pos  = (const float*)d_in[2];
    const float* Wins = (const float*)d_in[3];
    const float* cw   = (const float*)d_in[4];
    const float* cb   = (const float*)d_in[5];
    const float* dtb  = (const float*)d_in[6];
    const float* Alog = (const float*)d_in[7];
    const float* Dpar = (const float*)d_in[8];
    const float* nw   = (const float*)d_in[9];
    const float* Wout = (const float*)d_in[10];
    const float* pw   = (const float*)d_in[11];
    const float* pb   = (const float*)d_in[12];
    const float* c1w  = (const float*)d_in[13];
    const float* c1b  = (const float*)d_in[14];
    const float* c2w  = (const float*)d_in[15];
    const float* c2b  = (const float*)d_in[16];
    float* out = (float*)d_out;

    float* ws = (float*)d_ws;
    float* x      = ws;                 // 524288
    float* zx     = x + 524288;         // 2375680
    float* y      = zx + 2375680;       // 1048576
    float* Sbuf   = y + 1048576;        // 1048576
    float* Ctil   = Sbuf + 1048576;     // 1048576
    float* decay  = Ctil + 1048576;     // 256
    float* pooled = decay + 256;        // 512
    float* psum   = pooled + 512;       // 8192
    float* pmax   = psum + 8192;        // 8192

    void* args[] = {(void*)&ids, (void*)&emb, (void*)&pos, (void*)&Wins,
                    (void*)&cw, (void*)&cb, (void*)&dtb, (void*)&Alog,
                    (void*)&Dpar, (void*)&nw, (void*)&Wout, (void*)&pw,
                    (void*)&pb, (void*)&c1w, (void*)&c1b, (void*)&c2w,
                    (void*)&c2b, (void*)&out, (void*)&x, (void*)&zx,
                    (void*)&y, (void*)&Sbuf, (void*)&Ctil, (void*)&decay,
                    (void*)&pooled, (void*)&psum, (void*)&pmax};
    hipLaunchCooperativeKernel((void*)mega, dim3(NBLK), dim3(NTHR), args, 0, stream);
}

// Round 7
// 656.258 us; speedup vs baseline: 2.3248x; 2.3248x over previous
//
#include <hip/hip_runtime.h>
#include <math.h>

#define D_ 256
#define NL_ 4
#define NC_ 2
#define L_LEN 1024
#define NSTATE_ 64
#define DIN_ 512
#define H_ 8
#define P_ 64
#define CONVDIM_ 640
#define DPROJ_ 1160
#define EPS_ 1e-5f
#define NCH_ 16

__device__ __forceinline__ float siluf(float x) { return x / (1.f + __expf(-x)); }
__device__ __forceinline__ float geluf(float x) { return 0.5f * x * (1.f + erff(x * 0.70710678118654752f)); }

// x[b,l,d] = emb[ids[b,l], d] + pos[l, d]
__global__ void k_embed(const int* __restrict__ ids, const float* __restrict__ emb,
                        const float* __restrict__ pos, float* __restrict__ x, int total) {
    int i = blockIdx.x * blockDim.x + threadIdx.x;
    if (i >= total) return;
    int d = i & (D_ - 1);
    int bl = i >> 8;
    int l = bl & (L_LEN - 1);
    x[i] = emb[ids[bl] * D_ + d] + pos[l * D_ + d];
}

// C[M,N] = A[M,K] * B[N,K]^T ; BM=128,BN=64,BK=16; 8x4/thread; reg prefetch.
#define AS_(k, r) Asm[(k) * 132 + (r)]
#define BS_(k, r) Bsm[(k) * 68 + (r)]
__global__ void __launch_bounds__(256) gemm_f32t(const float* __restrict__ A,
        const float* __restrict__ B, float* __restrict__ C,
        int M, int N, int K) {
    __shared__ float Asm[16 * 132];
    __shared__ float Bsm[16 * 68];
    const int tid = threadIdx.x;
    const int row0 = blockIdx.y * 128;
    const int col0 = blockIdx.x * 64;
    const int arow = tid >> 2;
    const int akq = (tid & 3) * 4;
    const int brow = col0 + arow;
    const bool bok = brow < N;

    float4 pa0, pa1, pb0;
    {
        const float* a0 = &A[(size_t)(row0 + arow) * K + akq];
        pa0 = *(const float4*)a0;
        pa1 = *(const float4*)(a0 + (size_t)64 * K);
        pb0 = bok ? *(const float4*)&B[(size_t)brow * K + akq]
                  : float4{0.f, 0.f, 0.f, 0.f};
    }
    const int tm = tid >> 4;
    const int tn = tid & 15;
    float acc[8][4] = {};
    for (int k0 = 0; k0 < K; k0 += 16) {
        __syncthreads();
        AS_(akq + 0, arow) = pa0.x;
        AS_(akq + 1, arow) = pa0.y;
        AS_(akq + 2, arow) = pa0.z;
        AS_(akq + 3, arow) = pa0.w;
        AS_(akq + 0, arow + 64) = pa1.x;
        AS_(akq + 1, arow + 64) = pa1.y;
        AS_(akq + 2, arow + 64) = pa1.z;
        AS_(akq + 3, arow + 64) = pa1.w;
        BS_(akq + 0, arow) = pb0.x;
        BS_(akq + 1, arow) = pb0.y;
        BS_(akq + 2, arow) = pb0.z;
        BS_(akq + 3, arow) = pb0.w;
        __syncthreads();
        if (k0 + 16 < K) {
            const float* a0 = &A[(size_t)(row0 + arow) * K + k0 + 16 + akq];
            pa0 = *(const float4*)a0;
            pa1 = *(const float4*)(a0 + (size_t)64 * K);
            pb0 = bok ? *(const float4*)&B[(size_t)brow * K + k0 + 16 + akq]
                      : float4{0.f, 0.f, 0.f, 0.f};
        }
#pragma unroll
        for (int kk = 0; kk < 16; ++kk) {
            float a[8], b[4];
#pragma unroll
            for (int i = 0; i < 8; ++i) a[i] = AS_(kk, tm * 8 + i);
#pragma unroll
            for (int j = 0; j < 4; ++j) b[j] = BS_(kk, tn * 4 + j);
#pragma unroll
            for (int i = 0; i < 8; ++i)
#pragma unroll
                for (int j = 0; j < 4; ++j) acc[i][j] += a[i] * b[j];
        }
    }
    int cbase = col0 + tn * 4;
#pragma unroll
    for (int i = 0; i < 8; ++i) {
        size_t r = (size_t)(row0 + tm * 8 + i) * N + cbase;
        if (cbase + 3 < N) {
            float4 v = {acc[i][0], acc[i][1], acc[i][2], acc[i][3]};
            *(float4*)&C[r] = v;
        } else {
#pragma unroll
            for (int j = 0; j < 4; ++j)
                if (cbase + j < N) C[r + j] = acc[i][j];
        }
    }
}

// Fused SSM: conv+silu + dt + S_local + decay + Ctil + G(masked,transposed) + intra Y.
__global__ void __launch_bounds__(256) k_ssmA(const float* __restrict__ zx,
        const float* __restrict__ cw, const float* __restrict__ cb,
        const float* __restrict__ dtbias, const float* __restrict__ Alog,
        const float* __restrict__ Dp,
        float* __restrict__ Sbuf, float* __restrict__ decay,
        float* __restrict__ Ctil, float* __restrict__ y) {
    __shared__ float U[64][65];   // X[j][p]
    __shared__ float V[64][65];   // B[j][n]; later Wt[j][i]
    __shared__ float W[64][65];   // C[i][n]
    __shared__ float sdt[64], cs[64], wj[64];
    const int c = blockIdx.x, bh = blockIdx.y;
    const int b = bh >> 3, h = bh & 7;
    const int l0 = c << 6;
    const int tid = threadIdx.x, wid = tid >> 6, lane = tid & 63;

    const int chx = h * P_ + lane;
    const int chb = DIN_ + lane;
    const int chc = DIN_ + NSTATE_ + lane;
    float wx0 = cw[chx * 4], wx1 = cw[chx * 4 + 1], wx2 = cw[chx * 4 + 2], wx3 = cw[chx * 4 + 3];
    float wb0 = cw[chb * 4], wb1 = cw[chb * 4 + 1], wb2 = cw[chb * 4 + 2], wb3 = cw[chb * 4 + 3];
    float wc0 = cw[chc * 4], wc1 = cw[chc * 4 + 1], wc2 = cw[chc * 4 + 2], wc3 = cw[chc * 4 + 3];
    float bx = cb[chx], bb = cb[chb], bc = cb[chc];

    for (int r = 0; r < 64; r += 4) {
        int j = r + wid;
        int l = l0 + j;
        float ax = bx, ab = bb, ac = bc;
#pragma unroll
        for (int k = 0; k < 4; ++k) {
            int t = l - 3 + k;
            if (t >= 0) {
                const float* row = zx + (size_t)(b * L_LEN + t) * DPROJ_;
                float wxk = (k == 0) ? wx0 : (k == 1) ? wx1 : (k == 2) ? wx2 : wx3;
                float wbk = (k == 0) ? wb0 : (k == 1) ? wb1 : (k == 2) ? wb2 : wb3;
                float wck = (k == 0) ? wc0 : (k == 1) ? wc1 : (k == 2) ? wc2 : wc3;
                ax += wxk * row[DIN_ + chx];
                ab += wbk * row[DIN_ + chb];
                ac += wck * row[DIN_ + chc];
            }
        }
        U[j][lane] = siluf(ax);
        V[j][lane] = siluf(ab);
        W[j][lane] = siluf(ac);
    }
    if (tid < 64) {
        float xv = zx[(size_t)(b * L_LEN + l0 + tid) * DPROJ_ + (DPROJ_ - H_) + h] + dtbias[h];
        float sp = fmaxf(xv, 0.f) + log1pf(__expf(-fabsf(xv)));
        sdt[tid] = sp;
        cs[tid] = sp * (-__expf(Alog[h]));
    }
    __syncthreads();
    if (tid == 0) {
        float s = 0.f;
        for (int j = 0; j < 64; ++j) { s += cs[j]; cs[j] = s; }
    }
    __syncthreads();
    if (tid < 64) wj[tid] = __expf(cs[63] - cs[tid]) * sdt[tid];
    if (tid == 0) decay[bh * NCH_ + c] = __expf(cs[63]);
    __syncthreads();

    const int t4 = (tid & 15) * 4;
    const int r4 = (tid >> 4) * 4;
    const size_t sbase = (size_t)(bh * NCH_ + c) * 4096;

    // S_local[p][n]
    {
        float acc[4][4] = {};
        for (int j = 0; j < 64; ++j) {
            float w = wj[j];
            float4 xv = *(const float4*)&U[j][r4];
            float4 bv = *(const float4*)&V[j][t4];
            float xw[4] = {xv.x * w, xv.y * w, xv.z * w, xv.w * w};
#pragma unroll
            for (int ii = 0; ii < 4; ++ii) {
                acc[ii][0] += xw[ii] * bv.x;
                acc[ii][1] += xw[ii] * bv.y;
                acc[ii][2] += xw[ii] * bv.z;
                acc[ii][3] += xw[ii] * bv.w;
            }
        }
#pragma unroll
        for (int ii = 0; ii < 4; ++ii) {
            float4 v = {acc[ii][0], acc[ii][1], acc[ii][2], acc[ii][3]};
            *(float4*)&Sbuf[sbase + (size_t)(r4 + ii) * 64 + t4] = v;
        }
    }
    // Ctil[i][n] = e^{cs[i]} * C[i][n]
    for (int r = 0; r < 64; r += 4) {
        int ii = r + wid;
        Ctil[sbase + ii * 64 + lane] = __expf(cs[ii]) * W[ii][lane];
    }
    // G + masked transpose
    float g[4][4] = {};
    for (int ng = 0; ng < 64; ng += 4) {
        float4 cf[4], bf[4];
#pragma unroll
        for (int ii = 0; ii < 4; ++ii) cf[ii] = *(const float4*)&W[r4 + ii][ng];
#pragma unroll
        for (int jj = 0; jj < 4; ++jj) bf[jj] = *(const float4*)&V[t4 + jj][ng];
#pragma unroll
        for (int ii = 0; ii < 4; ++ii)
#pragma unroll
            for (int jj = 0; jj < 4; ++jj)
                g[ii][jj] += cf[ii].x * bf[jj].x + cf[ii].y * bf[jj].y +
                             cf[ii].z * bf[jj].z + cf[ii].w * bf[jj].w;
    }
    float wt[4][4];
#pragma unroll
    for (int ii = 0; ii < 4; ++ii) {
        int i = r4 + ii;
        float csi = cs[i];
#pragma unroll
        for (int jj = 0; jj < 4; ++jj) {
            int j = t4 + jj;
            wt[ii][jj] = (j <= i) ? __expf(fminf(csi - cs[j], 0.f)) * sdt[j] * g[ii][jj] : 0.f;
        }
    }
    __syncthreads();
#pragma unroll
    for (int jj = 0; jj < 4; ++jj) {
        float4 v = {wt[0][jj], wt[1][jj], wt[2][jj], wt[3][jj]};
        *(float4*)&V[t4 + jj][r4] = v;
    }
    __syncthreads();
    // intra Y
    {
        float acc[4][4] = {};
        for (int j = 0; j < 64; ++j) {
            float4 wv = *(const float4*)&V[j][r4];
            float4 xv = *(const float4*)&U[j][t4];
            float ws[4] = {wv.x, wv.y, wv.z, wv.w};
#pragma unroll
            for (int ii = 0; ii < 4; ++ii) {
                acc[ii][0] += ws[ii] * xv.x;
                acc[ii][1] += ws[ii] * xv.y;
                acc[ii][2] += ws[ii] * xv.z;
                acc[ii][3] += ws[ii] * xv.w;
            }
        }
        float Dh = Dp[h];
#pragma unroll
        for (int ii = 0; ii < 4; ++ii) {
            float4 xv = *(const float4*)&U[r4 + ii][t4];
            float4 v = {acc[ii][0] + Dh * xv.x, acc[ii][1] + Dh * xv.y,
                        acc[ii][2] + Dh * xv.z, acc[ii][3] + Dh * xv.w};
            *(float4*)&y[(size_t)(b * L_LEN + l0 + r4 + ii) * DIN_ + h * P_ + t4] = v;
        }
    }
}

// inter-chunk (scan fused): S_in[c] = sum_{c'<c} (prod_{k=c'+1..c-1} dec_k) S_local[c']
// then y[l0+i, h*64+p] += sum_n Ctil[i][n] * S_in[p][n].  Grid: (15, 16), c = bx+1.
__global__ void __launch_bounds__(256) k_inter(const float* __restrict__ Sbuf,
        const float* __restrict__ Ctil, const float* __restrict__ decay,
        float* __restrict__ y) {
    __shared__ float Sm[64][65];
    __shared__ float Cm[64][65];
    const int c = blockIdx.x + 1, bh = blockIdx.y;
    const int b = bh >> 3, h = bh & 7;
    const int l0 = c << 6;
    const int tid = threadIdx.x, wid = tid >> 6, lane = tid & 63;
    const size_t bhbase = (size_t)bh * NCH_ * 4096;

    float dec[NCH_];
#pragma unroll
    for (int k = 0; k < NCH_; ++k) dec[k] = decay[bh * NCH_ + k];

    float acc16[16] = {};
    float wgt = 1.f;
    for (int cp = c - 1; cp >= 0; --cp) {
        const float* src = Sbuf + bhbase + (size_t)cp * 4096;
#pragma unroll
        for (int i = 0; i < 16; ++i) acc16[i] += wgt * src[i * 256 + tid];
        wgt *= dec[cp];
    }
#pragma unroll
    for (int i = 0; i < 16; ++i) Sm[i * 4 + wid][lane] = acc16[i];

    const size_t base = bhbase + (size_t)c * 4096;
    for (int r = 0; r < 64; r += 4) {
        int pp = r + wid;
        Cm[pp][lane] = Ctil[base + pp * 64 + lane];
    }
    __syncthreads();
    const int t4 = (tid & 15) * 4;   // p group
    const int r4 = (tid >> 4) * 4;   // i group
    float acc[4][4] = {};
    for (int ng = 0; ng < 64; ng += 4) {
        float4 cf[4], sf[4];
#pragma unroll
        for (int ii = 0; ii < 4; ++ii) cf[ii] = *(const float4*)&Cm[r4 + ii][ng];
#pragma unroll
        for (int pp = 0; pp < 4; ++pp) sf[pp] = *(const float4*)&Sm[t4 + pp][ng];
#pragma unroll
        for (int ii = 0; ii < 4; ++ii)
#pragma unroll
            for (int pp = 0; pp < 4; ++pp)
                acc[ii][pp] += cf[ii].x * sf[pp].x + cf[ii].y * sf[pp].y +
                               cf[ii].z * sf[pp].z + cf[ii].w * sf[pp].w;
    }
#pragma unroll
    for (int ii = 0; ii < 4; ++ii) {
        float* dst = &y[(size_t)(b * L_LEN + l0 + r4 + ii) * DIN_ + h * P_ + t4];
        float4 v = *(const float4*)dst;
        v.x += acc[ii][0]; v.y += acc[ii][1]; v.z += acc[ii][2]; v.w += acc[ii][3];
        *(float4*)dst = v;
    }
}

// out-proj with fused gated RMSNorm: x += rmsnorm(y*silu(z))*nw @ Wol^T
// grid (4, 16, 4): col-tile, row-tile(128), k-slice(128). atomicAdd epilogue.
__global__ void __launch_bounds__(256) gemm_outg(const float* __restrict__ y,
        const float* __restrict__ zx, const float* __restrict__ nw,
        const float* __restrict__ Wol, float* __restrict__ x) {
    __shared__ float Asm[16 * 132];
    __shared__ float Bsm[16 * 68];
    __shared__ float scale[128];
    const int tid = threadIdx.x;
    const int col0 = blockIdx.x * 64;
    const int row0 = blockIdx.y * 128;
    const int kbase = blockIdx.z * 128;
    // Phase 0: row scales
    {
        int wv = tid >> 6, lane = tid & 63;
        for (int r = wv; r < 128; r += 4) {
            const float* yr = y + (size_t)(row0 + r) * DIN_;
            const float* zr = zx + (size_t)(row0 + r) * DPROJ_;
            float ss = 0.f;
#pragma unroll
            for (int e = 0; e < 8; ++e) {
                float g = yr[lane + e * 64] * siluf(zr[lane + e * 64]);
                ss += g * g;
            }
#pragma unroll
            for (int o = 32; o; o >>= 1) ss += __shfl_xor(ss, o, 64);
            if (lane == 0) scale[r] = rsqrtf(ss * (1.f / DIN_) + EPS_);
        }
    }
    __syncthreads();
    const int arow = tid >> 2;
    const int akq = (tid & 3) * 4;
    const int tm = tid >> 4, tn = tid & 15;
    const float* yp0 = y + (size_t)(row0 + arow) * DIN_ + kbase + akq;
    const float* yp1 = yp0 + (size_t)64 * DIN_;
    const float* zp0 = zx + (size_t)(row0 + arow) * DPROJ_ + kbase + akq;
    const float* zp1 = zp0 + (size_t)64 * DPROJ_;
    const float* bp = Wol + (size_t)(col0 + arow) * DIN_ + kbase + akq;
    float4 py0 = *(const float4*)yp0;
    float4 pz0 = *(const float4*)zp0;
    float4 py1 = *(const float4*)yp1;
    float4 pz1 = *(const float4*)zp1;
    float4 pb0 = *(const float4*)bp;
    float4 pnw = *(const float4*)&nw[kbase + akq];
    float acc[8][4] = {};
    for (int k0 = 0; k0 < 128; k0 += 16) {
        float s0 = scale[arow], s1 = scale[arow + 64];
        float a0[4] = {py0.x * siluf(pz0.x) * s0 * pnw.x, py0.y * siluf(pz0.y) * s0 * pnw.y,
                       py0.z * siluf(pz0.z) * s0 * pnw.z, py0.w * siluf(pz0.w) * s0 * pnw.w};
        float a1[4] = {py1.x * siluf(pz1.x) * s1 * pnw.x, py1.y * siluf(pz1.y) * s1 * pnw.y,
                       py1.z * siluf(pz1.z) * s1 * pnw.z, py1.w * siluf(pz1.w) * s1 * pnw.w};
        __syncthreads();
#pragma unroll
        for (int j = 0; j < 4; ++j) {
            AS_(akq + j, arow) = a0[j];
            AS_(akq + j, arow + 64) = a1[j];
        }
        BS_(akq + 0, arow) = pb0.x;
        BS_(akq + 1, arow) = pb0.y;
        BS_(akq + 2, arow) = pb0.z;
        BS_(akq + 3, arow) = pb0.w;
        __syncthreads();
        if (k0 + 16 < 128) {
            py0 = *(const float4*)(yp0 + k0 + 16);
            pz0 = *(const float4*)(zp0 + k0 + 16);
            py1 = *(const float4*)(yp1 + k0 + 16);
            pz1 = *(const float4*)(zp1 + k0 + 16);
            pb0 = *(const float4*)(bp + k0 + 16);
            pnw = *(const float4*)&nw[kbase + k0 + 16 + akq];
        }
#pragma unroll
        for (int kk = 0; kk < 16; ++kk) {
            float a[8], b[4];
#pragma unroll
            for (int i = 0; i < 8; ++i) a[i] = AS_(kk, tm * 8 + i);
#pragma unroll
            for (int j = 0; j < 4; ++j) b[j] = BS_(kk, tn * 4 + j);
#pragma unroll
            for (int i = 0; i < 8; ++i)
#pragma unroll
                for (int j = 0; j < 4; ++j) acc[i][j] += a[i] * b[j];
        }
    }
    int cbase = col0 + tn * 4;
#pragma unroll
    for (int i = 0; i < 8; ++i) {
        size_t r = (size_t)(row0 + tm * 8 + i) * D_ + cbase;
#pragma unroll
        for (int j = 0; j < 4; ++j) atomicAdd(&x[r + j], acc[i][j]);
    }
}

// two-stage pooling, stage 1
__global__ void k_pool1(const float* __restrict__ x, float* __restrict__ psum,
                        float* __restrict__ pmax) {
    int b = blockIdx.y, ch = blockIdx.x, d = threadIdx.x;
    const float* xb = x + ((size_t)(b * L_LEN) + ch * 64) * D_ + d;
    float s = 0.f, m = -INFINITY;
    for (int l = 0; l < 64; ++l) {
        float v = xb[(size_t)l * D_];
        s += v;
        m = fmaxf(m, v);
    }
    psum[(b * 16 + ch) * D_ + d] = s;
    pmax[(b * 16 + ch) * D_ + d] = m;
}

// pooling stage 2 + classifier head, one block per batch
__global__ void k_poolhead(const float* __restrict__ psum, const float* __restrict__ pmax,
                           const float* __restrict__ pw, const float* __restrict__ pb,
                           const float* __restrict__ c1w, const float* __restrict__ c1b,
                           const float* __restrict__ c2w, const float* __restrict__ c2b,
                           float* __restrict__ out) {
    __shared__ float sp[256], s1[256], s2[128];
    int b = blockIdx.x, t = threadIdx.x;
    float s = 0.f, m = -INFINITY;
    for (int ch = 0; ch < 16; ++ch) {
        s += psum[(b * 16 + ch) * D_ + t];
        m = fmaxf(m, pmax[(b * 16 + ch) * D_ + t]);
    }
    sp[t] = (s * (1.f / L_LEN) + m) * 0.5f;
    __syncthreads();
    float acc = pb[t];
    for (int d = 0; d < 256; ++d) acc += sp[d] * pw[t * 256 + d];
    s1[t] = geluf(acc);
    __syncthreads();
    if (t < 128) {
        float a = c1b[t];
        for (int d = 0; d < 256; ++d) a += s1[d] * c1w[t * 256 + d];
        s2[t] = geluf(a);
    }
    __syncthreads();
    if (t < 2) {
        float a = c2b[t];
        for (int d = 0; d < 128; ++d) a += s2[d] * c2w[t * 128 + d];
        out[b * NC_ + t] = a;
    }
}

extern "C" void kernel_launch(void* const* d_in, const int* in_sizes, int n_in,
                              void* d_out, int out_size, void* d_ws, size_t ws_size,
                              hipStream_t stream) {
    const int* ids    = (const int*)d_in[0];
    const float* emb  = (const float*)d_in[1];
    const float* pos  = (const float*)d_in[2];
    const float* Wins = (const float*)d_in[3];
    const float* cw   = (const float*)d_in[4];
    const float* cb   = (const float*)d_in[5];
    const float* dtb  = (const float*)d_in[6];
    const float* Alog = (const float*)d_in[7];
    const float* Dpar = (const float*)d_in[8];
    const float* nw   = (const float*)d_in[9];
    const float* Wout = (const float*)d_in[10];
    const float* pw   = (const float*)d_in[11];
    const float* pb   = (const float*)d_in[12];
    const float* c1w  = (const float*)d_in[13];
    const float* c1b  = (const float*)d_in[14];
    const float* c2w  = (const float*)d_in[15];
    const float* c2b  = (const float*)d_in[16];
    float* out = (float*)d_out;

    float* ws = (float*)d_ws;
    float* x      = ws;                 // 524288
    float* zx     = x + 524288;         // 2375680
    float* y      = zx + 2375680;       // 1048576
    float* Sbuf   = y + 1048576;        // 1048576
    float* Ctil   = Sbuf + 1048576;     // 1048576
    float* decay  = Ctil + 1048576;     // 256
    float* psum   = decay + 256;        // 8192
    float* pmax   = psum + 8192;        // 8192

    k_embed<<<2048, 256, 0, stream>>>(ids, emb, pos, x, 524288);
    for (int i = 0; i < NL_; ++i) {
        gemm_f32t<<<dim3(19, 16), 256, 0, stream>>>(
            x, Wins + (size_t)i * DPROJ_ * D_, zx, 2048, DPROJ_, D_);
        k_ssmA<<<dim3(NCH_, 16), 256, 0, stream>>>(
            zx, cw + (size_t)i * CONVDIM_ * 4, cb + (size_t)i * CONVDIM_,
            dtb + i * H_, Alog + i * H_, Dpar + i * H_, Sbuf, decay, Ctil, y);
        k_inter<<<dim3(NCH_ - 1, 16), 256, 0, stream>>>(Sbuf, Ctil, decay, y);
        gemm_outg<<<dim3(4, 16, 4), 256, 0, stream>>>(
            y, zx, nw + (size_t)i * DIN_, Wout + (size_t)i * D_ * DIN_, x);
    }
    k_pool1<<<dim3(16, 2), 256, 0, stream>>>(x, psum, pmax);
    k_poolhead<<<2, 256, 0, stream>>>(psum, pmax, pw, pb, c1w, c1b, c2w, c2b, out);
}

// Round 8
// 561.566 us; speedup vs baseline: 2.7169x; 1.1686x over previous
//
#include <hip/hip_runtime.h>
#include <math.h>

#define D_ 256
#define NL_ 4
#define NC_ 2
#define L_LEN 1024
#define NSTATE_ 64
#define DIN_ 512
#define H_ 8
#define P_ 64
#define CONVDIM_ 640
#define DPROJ_ 1160
#define EPS_ 1e-5f
#define NCH_ 16

__device__ __forceinline__ float siluf(float x) { return x / (1.f + __expf(-x)); }
__device__ __forceinline__ float geluf(float x) { return 0.5f * x * (1.f + erff(x * 0.70710678118654752f)); }

// x[b,l,d] = emb[ids[b,l], d] + pos[l, d]
__global__ void k_embed(const int* __restrict__ ids, const float* __restrict__ emb,
                        const float* __restrict__ pos, float* __restrict__ x, int total) {
    int i = blockIdx.x * blockDim.x + threadIdx.x;
    if (i >= total) return;
    int d = i & (D_ - 1);
    int bl = i >> 8;
    int l = bl & (L_LEN - 1);
    x[i] = emb[ids[bl] * D_ + d] + pos[l * D_ + d];
}

// C[M,N] (+)= A[M,K_total] * B[N,K_total]^T over k-range [blockIdx.z*kchunk, +kchunk)
// BM=128, BN=64, BK=16; 256 threads, 8x4/thread; reg prefetch.
#define AS_(k, r) Asm[(k) * 132 + (r)]
#define BS_(k, r) Bsm[(k) * 68 + (r)]
template <bool ATOMIC>
__global__ void __launch_bounds__(256) gemm_f32t(const float* __restrict__ A,
        const float* __restrict__ B, float* __restrict__ C,
        int M, int N, int K, int kchunk) {
    __shared__ float Asm[16 * 132];
    __shared__ float Bsm[16 * 68];
    const int tid = threadIdx.x;
    const int row0 = blockIdx.y * 128;
    const int col0 = blockIdx.x * 64;
    const int kbase = blockIdx.z * kchunk;
    const int arow = tid >> 2;
    const int akq = (tid & 3) * 4;
    const int brow = col0 + arow;
    const bool bok = brow < N;

    float4 pa0, pa1, pb0;
    {
        const float* a0 = &A[(size_t)(row0 + arow) * K + kbase + akq];
        pa0 = *(const float4*)a0;
        pa1 = *(const float4*)(a0 + (size_t)64 * K);
        pb0 = bok ? *(const float4*)&B[(size_t)brow * K + kbase + akq]
                  : float4{0.f, 0.f, 0.f, 0.f};
    }
    const int tm = tid >> 4;
    const int tn = tid & 15;
    float acc[8][4] = {};
    const int kend = kbase + kchunk;
    for (int k0 = kbase; k0 < kend; k0 += 16) {
        __syncthreads();
        AS_(akq + 0, arow) = pa0.x;
        AS_(akq + 1, arow) = pa0.y;
        AS_(akq + 2, arow) = pa0.z;
        AS_(akq + 3, arow) = pa0.w;
        AS_(akq + 0, arow + 64) = pa1.x;
        AS_(akq + 1, arow + 64) = pa1.y;
        AS_(akq + 2, arow + 64) = pa1.z;
        AS_(akq + 3, arow + 64) = pa1.w;
        BS_(akq + 0, arow) = pb0.x;
        BS_(akq + 1, arow) = pb0.y;
        BS_(akq + 2, arow) = pb0.z;
        BS_(akq + 3, arow) = pb0.w;
        __syncthreads();
        if (k0 + 16 < kend) {
            const float* a0 = &A[(size_t)(row0 + arow) * K + k0 + 16 + akq];
            pa0 = *(const float4*)a0;
            pa1 = *(const float4*)(a0 + (size_t)64 * K);
            pb0 = bok ? *(const float4*)&B[(size_t)brow * K + k0 + 16 + akq]
                      : float4{0.f, 0.f, 0.f, 0.f};
        }
#pragma unroll
        for (int kk = 0; kk < 16; ++kk) {
            float a[8], b[4];
#pragma unroll
            for (int i = 0; i < 8; ++i) a[i] = AS_(kk, tm * 8 + i);
#pragma unroll
            for (int j = 0; j < 4; ++j) b[j] = BS_(kk, tn * 4 + j);
#pragma unroll
            for (int i = 0; i < 8; ++i)
#pragma unroll
                for (int j = 0; j < 4; ++j) acc[i][j] += a[i] * b[j];
        }
    }
    int cbase = col0 + tn * 4;
#pragma unroll
    for (int i = 0; i < 8; ++i) {
        size_t r = (size_t)(row0 + tm * 8 + i) * N + cbase;
        if (ATOMIC) {
            if (cbase < N) {
#pragma unroll
                for (int j = 0; j < 4; ++j) atomicAdd(&C[r + j], acc[i][j]);
            }
        } else {
            if (cbase + 3 < N) {
                float4 v = {acc[i][0], acc[i][1], acc[i][2], acc[i][3]};
                *(float4*)&C[r] = v;
            } else {
#pragma unroll
                for (int j = 0; j < 4; ++j)
                    if (cbase + j < N) C[r + j] = acc[i][j];
            }
        }
    }
}

// Fused SSM: conv+silu + dt + S_local + decay + Ctil + G(masked,transposed) + intra Y.
__global__ void __launch_bounds__(256) k_ssmA(const float* __restrict__ zx,
        const float* __restrict__ cw, const float* __restrict__ cb,
        const float* __restrict__ dtbias, const float* __restrict__ Alog,
        const float* __restrict__ Dp,
        float* __restrict__ Sbuf, float* __restrict__ decay,
        float* __restrict__ Ctil, float* __restrict__ y) {
    __shared__ float U[64][65];
    __shared__ float V[64][65];
    __shared__ float W[64][65];
    __shared__ float sdt[64], cs[64], wj[64];
    const int c = blockIdx.x, bh = blockIdx.y;
    const int b = bh >> 3, h = bh & 7;
    const int l0 = c << 6;
    const int tid = threadIdx.x, wid = tid >> 6, lane = tid & 63;

    const int chx = h * P_ + lane;
    const int chb = DIN_ + lane;
    const int chc = DIN_ + NSTATE_ + lane;
    float wx0 = cw[chx * 4], wx1 = cw[chx * 4 + 1], wx2 = cw[chx * 4 + 2], wx3 = cw[chx * 4 + 3];
    float wb0 = cw[chb * 4], wb1 = cw[chb * 4 + 1], wb2 = cw[chb * 4 + 2], wb3 = cw[chb * 4 + 3];
    float wc0 = cw[chc * 4], wc1 = cw[chc * 4 + 1], wc2 = cw[chc * 4 + 2], wc3 = cw[chc * 4 + 3];
    float bx = cb[chx], bb = cb[chb], bc = cb[chc];

    for (int r = 0; r < 64; r += 4) {
        int j = r + wid;
        int l = l0 + j;
        float ax = bx, ab = bb, ac = bc;
#pragma unroll
        for (int k = 0; k < 4; ++k) {
            int t = l - 3 + k;
            if (t >= 0) {
                const float* row = zx + (size_t)(b * L_LEN + t) * DPROJ_;
                float wxk = (k == 0) ? wx0 : (k == 1) ? wx1 : (k == 2) ? wx2 : wx3;
                float wbk = (k == 0) ? wb0 : (k == 1) ? wb1 : (k == 2) ? wb2 : wb3;
                float wck = (k == 0) ? wc0 : (k == 1) ? wc1 : (k == 2) ? wc2 : wc3;
                ax += wxk * row[DIN_ + chx];
                ab += wbk * row[DIN_ + chb];
                ac += wck * row[DIN_ + chc];
            }
        }
        U[j][lane] = siluf(ax);
        V[j][lane] = siluf(ab);
        W[j][lane] = siluf(ac);
    }
    if (tid < 64) {
        float xv = zx[(size_t)(b * L_LEN + l0 + tid) * DPROJ_ + (DPROJ_ - H_) + h] + dtbias[h];
        float sp = fmaxf(xv, 0.f) + log1pf(__expf(-fabsf(xv)));
        sdt[tid] = sp;
        cs[tid] = sp * (-__expf(Alog[h]));
    }
    __syncthreads();
    if (tid == 0) {
        float s = 0.f;
        for (int j = 0; j < 64; ++j) { s += cs[j]; cs[j] = s; }
    }
    __syncthreads();
    if (tid < 64) wj[tid] = __expf(cs[63] - cs[tid]) * sdt[tid];
    if (tid == 0) decay[bh * NCH_ + c] = __expf(cs[63]);
    __syncthreads();

    const int t4 = (tid & 15) * 4;
    const int r4 = (tid >> 4) * 4;
    const size_t sbase = (size_t)(bh * NCH_ + c) * 4096;

    // S_local[p][n]
    {
        float acc[4][4] = {};
        for (int j = 0; j < 64; ++j) {
            float w = wj[j];
            float4 xv = *(const float4*)&U[j][r4];
            float4 bv = *(const float4*)&V[j][t4];
            float xw[4] = {xv.x * w, xv.y * w, xv.z * w, xv.w * w};
#pragma unroll
            for (int ii = 0; ii < 4; ++ii) {
                acc[ii][0] += xw[ii] * bv.x;
                acc[ii][1] += xw[ii] * bv.y;
                acc[ii][2] += xw[ii] * bv.z;
                acc[ii][3] += xw[ii] * bv.w;
            }
        }
#pragma unroll
        for (int ii = 0; ii < 4; ++ii) {
            float4 v = {acc[ii][0], acc[ii][1], acc[ii][2], acc[ii][3]};
            *(float4*)&Sbuf[sbase + (size_t)(r4 + ii) * 64 + t4] = v;
        }
    }
    // Ctil[i][n] = e^{cs[i]} * C[i][n]
    for (int r = 0; r < 64; r += 4) {
        int ii = r + wid;
        Ctil[sbase + ii * 64 + lane] = __expf(cs[ii]) * W[ii][lane];
    }
    // G + masked transpose
    float g[4][4] = {};
    for (int ng = 0; ng < 64; ng += 4) {
        float4 cf[4], bf[4];
#pragma unroll
        for (int ii = 0; ii < 4; ++ii) cf[ii] = *(const float4*)&W[r4 + ii][ng];
#pragma unroll
        for (int jj = 0; jj < 4; ++jj) bf[jj] = *(const float4*)&V[t4 + jj][ng];
#pragma unroll
        for (int ii = 0; ii < 4; ++ii)
#pragma unroll
            for (int jj = 0; jj < 4; ++jj)
                g[ii][jj] += cf[ii].x * bf[jj].x + cf[ii].y * bf[jj].y +
                             cf[ii].z * bf[jj].z + cf[ii].w * bf[jj].w;
    }
    float wt[4][4];
#pragma unroll
    for (int ii = 0; ii < 4; ++ii) {
        int i = r4 + ii;
        float csi = cs[i];
#pragma unroll
        for (int jj = 0; jj < 4; ++jj) {
            int j = t4 + jj;
            wt[ii][jj] = (j <= i) ? __expf(fminf(csi - cs[j], 0.f)) * sdt[j] * g[ii][jj] : 0.f;
        }
    }
    __syncthreads();
#pragma unroll
    for (int jj = 0; jj < 4; ++jj) {
        float4 v = {wt[0][jj], wt[1][jj], wt[2][jj], wt[3][jj]};
        *(float4*)&V[t4 + jj][r4] = v;
    }
    __syncthreads();
    // intra Y
    {
        float acc[4][4] = {};
        for (int j = 0; j < 64; ++j) {
            float4 wv = *(const float4*)&V[j][r4];
            float4 xv = *(const float4*)&U[j][t4];
            float ws[4] = {wv.x, wv.y, wv.z, wv.w};
#pragma unroll
            for (int ii = 0; ii < 4; ++ii) {
                acc[ii][0] += ws[ii] * xv.x;
                acc[ii][1] += ws[ii] * xv.y;
                acc[ii][2] += ws[ii] * xv.z;
                acc[ii][3] += ws[ii] * xv.w;
            }
        }
        float Dh = Dp[h];
#pragma unroll
        for (int ii = 0; ii < 4; ++ii) {
            float4 xv = *(const float4*)&U[r4 + ii][t4];
            float4 v = {acc[ii][0] + Dh * xv.x, acc[ii][1] + Dh * xv.y,
                        acc[ii][2] + Dh * xv.z, acc[ii][3] + Dh * xv.w};
            *(float4*)&y[(size_t)(b * L_LEN + l0 + r4 + ii) * DIN_ + h * P_ + t4] = v;
        }
    }
}

// inter-chunk with fused prefix scan: S_in[c] = sum_{c'<c} (prod dec) S_local[c'];
// y += Ctil · S_in.  Grid: (15, 16), c = bx+1.
__global__ void __launch_bounds__(256) k_inter(const float* __restrict__ Sbuf,
        const float* __restrict__ Ctil, const float* __restrict__ decay,
        float* __restrict__ y) {
    __shared__ float Sm[64][65];
    __shared__ float Cm[64][65];
    const int c = blockIdx.x + 1, bh = blockIdx.y;
    const int b = bh >> 3, h = bh & 7;
    const int l0 = c << 6;
    const int tid = threadIdx.x, wid = tid >> 6, lane = tid & 63;
    const size_t bhbase = (size_t)bh * NCH_ * 4096;

    float dec[NCH_];
#pragma unroll
    for (int k = 0; k < NCH_; ++k) dec[k] = decay[bh * NCH_ + k];

    float acc16[16] = {};
    float wgt = 1.f;
    for (int cp = c - 1; cp >= 0; --cp) {
        const float* src = Sbuf + bhbase + (size_t)cp * 4096;
#pragma unroll
        for (int i = 0; i < 16; ++i) acc16[i] += wgt * src[i * 256 + tid];
        wgt *= dec[cp];
    }
#pragma unroll
    for (int i = 0; i < 16; ++i) Sm[i * 4 + wid][lane] = acc16[i];

    const size_t base = bhbase + (size_t)c * 4096;
    for (int r = 0; r < 64; r += 4) {
        int pp = r + wid;
        Cm[pp][lane] = Ctil[base + pp * 64 + lane];
    }
    __syncthreads();
    const int t4 = (tid & 15) * 4;
    const int r4 = (tid >> 4) * 4;
    float acc[4][4] = {};
    for (int ng = 0; ng < 64; ng += 4) {
        float4 cf[4], sf[4];
#pragma unroll
        for (int ii = 0; ii < 4; ++ii) cf[ii] = *(const float4*)&Cm[r4 + ii][ng];
#pragma unroll
        for (int pp = 0; pp < 4; ++pp) sf[pp] = *(const float4*)&Sm[t4 + pp][ng];
#pragma unroll
        for (int ii = 0; ii < 4; ++ii)
#pragma unroll
            for (int pp = 0; pp < 4; ++pp)
                acc[ii][pp] += cf[ii].x * sf[pp].x + cf[ii].y * sf[pp].y +
                               cf[ii].z * sf[pp].z + cf[ii].w * sf[pp].w;
    }
#pragma unroll
    for (int ii = 0; ii < 4; ++ii) {
        float* dst = &y[(size_t)(b * L_LEN + l0 + r4 + ii) * DIN_ + h * P_ + t4];
        float4 v = *(const float4*)dst;
        v.x += acc[ii][0]; v.y += acc[ii][1]; v.z += acc[ii][2]; v.w += acc[ii][3];
        *(float4*)dst = v;
    }
}

// y = rmsnorm(y * silu(z)) * norm_w   (in place)
__global__ void k_gatenorm(const float* __restrict__ zx, const float* __restrict__ nw,
                           float* __restrict__ y) {
    __shared__ float sred[4];
    int bl = blockIdx.x;
    float* yr = y + (size_t)bl * DIN_;
    const float* zr = zx + (size_t)bl * DPROJ_;
    int t = threadIdx.x;
    float g0 = yr[t] * siluf(zr[t]);
    float g1 = yr[t + 256] * siluf(zr[t + 256]);
    float ss = g0 * g0 + g1 * g1;
#pragma unroll
    for (int o = 32; o; o >>= 1) ss += __shfl_xor(ss, o, 64);
    if ((t & 63) == 0) sred[t >> 6] = ss;
    __syncthreads();
    ss = sred[0] + sred[1] + sred[2] + sred[3];
    float scale = rsqrtf(ss * (1.f / DIN_) + EPS_);
    yr[t] = g0 * scale * nw[t];
    yr[t + 256] = g1 * scale * nw[t + 256];
}

// two-stage pooling, stage 1
__global__ void k_pool1(const float* __restrict__ x, float* __restrict__ psum,
                        float* __restrict__ pmax) {
    int b = blockIdx.y, ch = blockIdx.x, d = threadIdx.x;
    const float* xb = x + ((size_t)(b * L_LEN) + ch * 64) * D_ + d;
    float s = 0.f, m = -INFINITY;
    for (int l = 0; l < 64; ++l) {
        float v = xb[(size_t)l * D_];
        s += v;
        m = fmaxf(m, v);
    }
    psum[(b * 16 + ch) * D_ + d] = s;
    pmax[(b * 16 + ch) * D_ + d] = m;
}

// pooling stage 2 + classifier head
__global__ void k_poolhead(const float* __restrict__ psum, const float* __restrict__ pmax,
                           const float* __restrict__ pw, const float* __restrict__ pb,
                           const float* __restrict__ c1w, const float* __restrict__ c1b,
                           const float* __restrict__ c2w, const float* __restrict__ c2b,
                           float* __restrict__ out) {
    __shared__ float sp[256], s1[256], s2[128];
    int b = blockIdx.x, t = threadIdx.x;
    float s = 0.f, m = -INFINITY;
    for (int ch = 0; ch < 16; ++ch) {
        s += psum[(b * 16 + ch) * D_ + t];
        m = fmaxf(m, pmax[(b * 16 + ch) * D_ + t]);
    }
    sp[t] = (s * (1.f / L_LEN) + m) * 0.5f;
    __syncthreads();
    float acc = pb[t];
    for (int d = 0; d < 256; ++d) acc += sp[d] * pw[t * 256 + d];
    s1[t] = geluf(acc);
    __syncthreads();
    if (t < 128) {
        float a = c1b[t];
        for (int d = 0; d < 256; ++d) a += s1[d] * c1w[t * 256 + d];
        s2[t] = geluf(a);
    }
    __syncthreads();
    if (t < 2) {
        float a = c2b[t];
        for (int d = 0; d < 128; ++d) a += s2[d] * c2w[t * 128 + d];
        out[b * NC_ + t] = a;
    }
}

extern "C" void kernel_launch(void* const* d_in, const int* in_sizes, int n_in,
                              void* d_out, int out_size, void* d_ws, size_t ws_size,
                              hipStream_t stream) {
    const int* ids    = (const int*)d_in[0];
    const float* emb  = (const float*)d_in[1];
    const float* pos  = (const float*)d_in[2];
    const float* Wins = (const float*)d_in[3];
    const float* cw   = (const float*)d_in[4];
    const float* cb   = (const float*)d_in[5];
    const float* dtb  = (const float*)d_in[6];
    const float* Alog = (const float*)d_in[7];
    const float* Dpar = (const float*)d_in[8];
    const float* nw   = (const float*)d_in[9];
    const float* Wout = (const float*)d_in[10];
    const float* pw   = (const float*)d_in[11];
    const float* pb   = (const float*)d_in[12];
    const float* c1w  = (const float*)d_in[13];
    const float* c1b  = (const float*)d_in[14];
    const float* c2w  = (const float*)d_in[15];
    const float* c2b  = (const float*)d_in[16];
    float* out = (float*)d_out;

    float* ws = (float*)d_ws;
    float* x      = ws;                 // 524288
    float* zx     = x + 524288;         // 2375680
    float* y      = zx + 2375680;       // 1048576
    float* Sbuf   = y + 1048576;        // 1048576
    float* Ctil   = Sbuf + 1048576;     // 1048576
    float* decay  = Ctil + 1048576;     // 256
    float* psum   = decay + 256;        // 8192
    float* pmax   = psum + 8192;        // 8192

    k_embed<<<2048, 256, 0, stream>>>(ids, emb, pos, x, 524288);
    for (int i = 0; i < NL_; ++i) {
        gemm_f32t<false><<<dim3(19, 16, 1), 256, 0, stream>>>(
            x, Wins + (size_t)i * DPROJ_ * D_, zx, 2048, DPROJ_, D_, D_);
        k_ssmA<<<dim3(NCH_, 16), 256, 0, stream>>>(
            zx, cw + (size_t)i * CONVDIM_ * 4, cb + (size_t)i * CONVDIM_,
            dtb + i * H_, Alog + i * H_, Dpar + i * H_, Sbuf, decay, Ctil, y);
        k_inter<<<dim3(NCH_ - 1, 16), 256, 0, stream>>>(Sbuf, Ctil, decay, y);
        k_gatenorm<<<2048, 256, 0, stream>>>(zx, nw + (size_t)i * DIN_, y);
        gemm_f32t<true><<<dim3(4, 16, 4), 256, 0, stream>>>(
            y, Wout + (size_t)i * D_ * DIN_, x, 2048, D_, DIN_, 128);
    }
    k_pool1<<<dim3(16, 2), 256, 0, stream>>>(x, psum, pmax);
    k_poolhead<<<2, 256, 0, stream>>>(psum, pmax, pw, pb, c1w, c1b, c2w, c2b, out);
}

// Round 9
// 417.453 us; speedup vs baseline: 3.6548x; 1.3452x over previous
//
#include <hip/hip_runtime.h>
#include <math.h>

#define D_ 256
#define NL_ 4
#define NC_ 2
#define L_LEN 1024
#define NSTATE_ 64
#define DIN_ 512
#define H_ 8
#define P_ 64
#define CONVDIM_ 640
#define DPROJ_ 1160
#define EPS_ 1e-5f
#define NCH_ 16

typedef __attribute__((ext_vector_type(8))) short short8;
typedef __attribute__((ext_vector_type(4))) float f32x4;
typedef __attribute__((ext_vector_type(4))) unsigned short us4;

__device__ __forceinline__ float siluf(float x) { return x / (1.f + __expf(-x)); }
__device__ __forceinline__ float geluf(float x) { return 0.5f * x * (1.f + erff(x * 0.70710678118654752f)); }
__device__ __forceinline__ unsigned short f2bf(float f) {
    unsigned u = __float_as_uint(f);
    u += 0x7FFFu + ((u >> 16) & 1u);
    return (unsigned short)(u >> 16);
}
__device__ __forceinline__ float bf2f(unsigned short h) {
    return __uint_as_float(((unsigned)h) << 16);
}

// x[b,l,d] = emb[ids[b,l], d] + pos[l, d]
__global__ void k_embed(const int* __restrict__ ids, const float* __restrict__ emb,
                        const float* __restrict__ pos, float* __restrict__ x, int total) {
    int i = blockIdx.x * blockDim.x + threadIdx.x;
    if (i >= total) return;
    int d = i & (D_ - 1);
    int bl = i >> 8;
    int l = bl & (L_LEN - 1);
    x[i] = emb[ids[bl] * D_ + d] + pos[l * D_ + d];
}

// split f32 weights into bf16 hi/lo planes
__global__ void k_w2bf(const float* __restrict__ W, unsigned short* __restrict__ hi,
                       unsigned short* __restrict__ lo, int n) {
    int i = blockIdx.x * blockDim.x + threadIdx.x;
    if (i >= n) return;
    float f = W[i];
    unsigned short h = f2bf(f);
    hi[i] = h;
    lo[i] = f2bf(f - bf2f(h));
}

// C[M,N] (+)= A[M,K] * B[N,K]^T via bf16x3 MFMA. BM=128, BN=64, BK=32.
// A: f32 (split inline). B: pre-split bf16 hi/lo planes, row-major [N][K].
// grid (colTiles, rowTiles, kSlices); kchunk per slice (multiple of 32).
template <bool ATOMIC>
__global__ void __launch_bounds__(256) gemm_bf3(const float* __restrict__ A,
        const unsigned short* __restrict__ Bhi, const unsigned short* __restrict__ Blo,
        float* __restrict__ C, int M, int N, int K, int kchunk) {
    __shared__ __align__(16) unsigned short Ah[128 * 40];
    __shared__ __align__(16) unsigned short Al[128 * 40];
    __shared__ __align__(16) unsigned short Bh[64 * 40];
    __shared__ __align__(16) unsigned short Bl[64 * 40];
    const int tid = threadIdx.x;
    const int col0 = blockIdx.x * 64;
    const int row0 = blockIdx.y * 128;
    const int kbase = blockIdx.z * kchunk;

    const int sar = tid >> 1, sas = (tid & 1) * 16;   // A staging: row, k-seg
    const int sbr = tid >> 2, sbs = (tid & 3) * 8;    // B staging: n, k-seg
    const bool bok = (col0 + sbr) < N;
    const float* aptr = A + (size_t)(row0 + sar) * K + kbase + sas;
    const unsigned short* bhptr = Bhi + (size_t)(col0 + sbr) * K + kbase + sbs;
    const unsigned short* blptr = Blo + (size_t)(col0 + sbr) * K + kbase + sbs;

    float4 pa[4];
    short8 pbh = {0, 0, 0, 0, 0, 0, 0, 0}, pbl = {0, 0, 0, 0, 0, 0, 0, 0};
#pragma unroll
    for (int i = 0; i < 4; ++i) pa[i] = *(const float4*)(aptr + i * 4);
    if (bok) {
        pbh = *(const short8*)bhptr;
        pbl = *(const short8*)blptr;
    }

    const int wave = tid >> 6, lane = tid & 63;
    const int lq = lane >> 4, lm = lane & 15;
    f32x4 acc[2][4] = {};
    const int nsteps = kchunk >> 5;
    for (int s = 0; s < nsteps; ++s) {
        __syncthreads();
#pragma unroll
        for (int i = 0; i < 4; ++i) {
            float4 f = pa[i];
            unsigned short h0 = f2bf(f.x), h1 = f2bf(f.y), h2 = f2bf(f.z), h3 = f2bf(f.w);
            us4 hv = {h0, h1, h2, h3};
            us4 lv = {f2bf(f.x - bf2f(h0)), f2bf(f.y - bf2f(h1)),
                      f2bf(f.z - bf2f(h2)), f2bf(f.w - bf2f(h3))};
            *(us4*)&Ah[sar * 40 + sas + i * 4] = hv;
            *(us4*)&Al[sar * 40 + sas + i * 4] = lv;
        }
        *(short8*)&Bh[sbr * 40 + sbs] = pbh;
        *(short8*)&Bl[sbr * 40 + sbs] = pbl;
        __syncthreads();
        if (s + 1 < nsteps) {
            int ko = (s + 1) * 32;
#pragma unroll
            for (int i = 0; i < 4; ++i) pa[i] = *(const float4*)(aptr + ko + i * 4);
            if (bok) {
                pbh = *(const short8*)(bhptr + ko);
                pbl = *(const short8*)(blptr + ko);
            }
        }
        short8 bh[4], bl[4];
#pragma unroll
        for (int ct = 0; ct < 4; ++ct) {
            bh[ct] = *(const short8*)&Bh[(ct * 16 + lm) * 40 + lq * 8];
            bl[ct] = *(const short8*)&Bl[(ct * 16 + lm) * 40 + lq * 8];
        }
#pragma unroll
        for (int rt = 0; rt < 2; ++rt) {
            short8 ah = *(const short8*)&Ah[(wave * 32 + rt * 16 + lm) * 40 + lq * 8];
            short8 al = *(const short8*)&Al[(wave * 32 + rt * 16 + lm) * 40 + lq * 8];
#pragma unroll
            for (int ct = 0; ct < 4; ++ct) {
                acc[rt][ct] = __builtin_amdgcn_mfma_f32_16x16x32_bf16(ah, bh[ct], acc[rt][ct], 0, 0, 0);
                acc[rt][ct] = __builtin_amdgcn_mfma_f32_16x16x32_bf16(ah, bl[ct], acc[rt][ct], 0, 0, 0);
                acc[rt][ct] = __builtin_amdgcn_mfma_f32_16x16x32_bf16(al, bh[ct], acc[rt][ct], 0, 0, 0);
            }
        }
    }
    // D layout: col = lane&15, row = (lane>>4)*4 + reg  [m89-verified]
#pragma unroll
    for (int rt = 0; rt < 2; ++rt) {
#pragma unroll
        for (int ct = 0; ct < 4; ++ct) {
            int col = col0 + ct * 16 + lm;
            if (col >= N) continue;
            int rbase = row0 + wave * 32 + rt * 16 + lq * 4;
#pragma unroll
            for (int reg = 0; reg < 4; ++reg) {
                size_t idx = (size_t)(rbase + reg) * N + col;
                if (ATOMIC) atomicAdd(&C[idx], acc[rt][ct][reg]);
                else C[idx] = acc[rt][ct][reg];
            }
        }
    }
}

// Fused SSM: conv+silu + dt + S_local + decay + Ctil + G(masked,transposed) + intra Y.
__global__ void __launch_bounds__(256) k_ssmA(const float* __restrict__ zx,
        const float* __restrict__ cw, const float* __restrict__ cb,
        const float* __restrict__ dtbias, const float* __restrict__ Alog,
        const float* __restrict__ Dp,
        float* __restrict__ Sbuf, float* __restrict__ decay,
        float* __restrict__ Ctil, float* __restrict__ y) {
    __shared__ float U[64][65];
    __shared__ float V[64][65];
    __shared__ float W[64][65];
    __shared__ float sdt[64], cs[64], wj[64];
    const int c = blockIdx.x, bh = blockIdx.y;
    const int b = bh >> 3, h = bh & 7;
    const int l0 = c << 6;
    const int tid = threadIdx.x, wid = tid >> 6, lane = tid & 63;

    const int chx = h * P_ + lane;
    const int chb = DIN_ + lane;
    const int chc = DIN_ + NSTATE_ + lane;
    float wx0 = cw[chx * 4], wx1 = cw[chx * 4 + 1], wx2 = cw[chx * 4 + 2], wx3 = cw[chx * 4 + 3];
    float wb0 = cw[chb * 4], wb1 = cw[chb * 4 + 1], wb2 = cw[chb * 4 + 2], wb3 = cw[chb * 4 + 3];
    float wc0 = cw[chc * 4], wc1 = cw[chc * 4 + 1], wc2 = cw[chc * 4 + 2], wc3 = cw[chc * 4 + 3];
    float bx = cb[chx], bb = cb[chb], bc = cb[chc];

    for (int r = 0; r < 64; r += 4) {
        int j = r + wid;
        int l = l0 + j;
        float ax = bx, ab = bb, ac = bc;
#pragma unroll
        for (int k = 0; k < 4; ++k) {
            int t = l - 3 + k;
            if (t >= 0) {
                const float* row = zx + (size_t)(b * L_LEN + t) * DPROJ_;
                float wxk = (k == 0) ? wx0 : (k == 1) ? wx1 : (k == 2) ? wx2 : wx3;
                float wbk = (k == 0) ? wb0 : (k == 1) ? wb1 : (k == 2) ? wb2 : wb3;
                float wck = (k == 0) ? wc0 : (k == 1) ? wc1 : (k == 2) ? wc2 : wc3;
                ax += wxk * row[DIN_ + chx];
                ab += wbk * row[DIN_ + chb];
                ac += wck * row[DIN_ + chc];
            }
        }
        U[j][lane] = siluf(ax);
        V[j][lane] = siluf(ab);
        W[j][lane] = siluf(ac);
    }
    if (tid < 64) {
        float xv = zx[(size_t)(b * L_LEN + l0 + tid) * DPROJ_ + (DPROJ_ - H_) + h] + dtbias[h];
        float sp = fmaxf(xv, 0.f) + log1pf(__expf(-fabsf(xv)));
        sdt[tid] = sp;
        cs[tid] = sp * (-__expf(Alog[h]));
    }
    __syncthreads();
    if (tid == 0) {
        float s = 0.f;
        for (int j = 0; j < 64; ++j) { s += cs[j]; cs[j] = s; }
    }
    __syncthreads();
    if (tid < 64) wj[tid] = __expf(cs[63] - cs[tid]) * sdt[tid];
    if (tid == 0) decay[bh * NCH_ + c] = __expf(cs[63]);
    __syncthreads();

    const int t4 = (tid & 15) * 4;
    const int r4 = (tid >> 4) * 4;
    const size_t sbase = (size_t)(bh * NCH_ + c) * 4096;

    {
        float acc[4][4] = {};
        for (int j = 0; j < 64; ++j) {
            float w = wj[j];
            float4 xv = *(const float4*)&U[j][r4];
            float4 bv = *(const float4*)&V[j][t4];
            float xw[4] = {xv.x * w, xv.y * w, xv.z * w, xv.w * w};
#pragma unroll
            for (int ii = 0; ii < 4; ++ii) {
                acc[ii][0] += xw[ii] * bv.x;
                acc[ii][1] += xw[ii] * bv.y;
                acc[ii][2] += xw[ii] * bv.z;
                acc[ii][3] += xw[ii] * bv.w;
            }
        }
#pragma unroll
        for (int ii = 0; ii < 4; ++ii) {
            float4 v = {acc[ii][0], acc[ii][1], acc[ii][2], acc[ii][3]};
            *(float4*)&Sbuf[sbase + (size_t)(r4 + ii) * 64 + t4] = v;
        }
    }
    for (int r = 0; r < 64; r += 4) {
        int ii = r + wid;
        Ctil[sbase + ii * 64 + lane] = __expf(cs[ii]) * W[ii][lane];
    }
    float g[4][4] = {};
    for (int ng = 0; ng < 64; ng += 4) {
        float4 cf[4], bf[4];
#pragma unroll
        for (int ii = 0; ii < 4; ++ii) cf[ii] = *(const float4*)&W[r4 + ii][ng];
#pragma unroll
        for (int jj = 0; jj < 4; ++jj) bf[jj] = *(const float4*)&V[t4 + jj][ng];
#pragma unroll
        for (int ii = 0; ii < 4; ++ii)
#pragma unroll
            for (int jj = 0; jj < 4; ++jj)
                g[ii][jj] += cf[ii].x * bf[jj].x + cf[ii].y * bf[jj].y +
                             cf[ii].z * bf[jj].z + cf[ii].w * bf[jj].w;
    }
    float wt[4][4];
#pragma unroll
    for (int ii = 0; ii < 4; ++ii) {
        int i = r4 + ii;
        float csi = cs[i];
#pragma unroll
        for (int jj = 0; jj < 4; ++jj) {
            int j = t4 + jj;
            wt[ii][jj] = (j <= i) ? __expf(fminf(csi - cs[j], 0.f)) * sdt[j] * g[ii][jj] : 0.f;
        }
    }
    __syncthreads();
#pragma unroll
    for (int jj = 0; jj < 4; ++jj) {
        float4 v = {wt[0][jj], wt[1][jj], wt[2][jj], wt[3][jj]};
        *(float4*)&V[t4 + jj][r4] = v;
    }
    __syncthreads();
    {
        float acc[4][4] = {};
        for (int j = 0; j < 64; ++j) {
            float4 wv = *(const float4*)&V[j][r4];
            float4 xv = *(const float4*)&U[j][t4];
            float ws[4] = {wv.x, wv.y, wv.z, wv.w};
#pragma unroll
            for (int ii = 0; ii < 4; ++ii) {
                acc[ii][0] += ws[ii] * xv.x;
                acc[ii][1] += ws[ii] * xv.y;
                acc[ii][2] += ws[ii] * xv.z;
                acc[ii][3] += ws[ii] * xv.w;
            }
        }
        float Dh = Dp[h];
#pragma unroll
        for (int ii = 0; ii < 4; ++ii) {
            float4 xv = *(const float4*)&U[r4 + ii][t4];
            float4 v = {acc[ii][0] + Dh * xv.x, acc[ii][1] + Dh * xv.y,
                        acc[ii][2] + Dh * xv.z, acc[ii][3] + Dh * xv.w};
            *(float4*)&y[(size_t)(b * L_LEN + l0 + r4 + ii) * DIN_ + h * P_ + t4] = v;
        }
    }
}

// inter-chunk with fused prefix scan; grid (15, 16), c = bx+1.
__global__ void __launch_bounds__(256) k_inter(const float* __restrict__ Sbuf,
        const float* __restrict__ Ctil, const float* __restrict__ decay,
        float* __restrict__ y) {
    __shared__ float Sm[64][65];
    __shared__ float Cm[64][65];
    const int c = blockIdx.x + 1, bh = blockIdx.y;
    const int b = bh >> 3, h = bh & 7;
    const int l0 = c << 6;
    const int tid = threadIdx.x, wid = tid >> 6, lane = tid & 63;
    const size_t bhbase = (size_t)bh * NCH_ * 4096;

    float dec[NCH_];
#pragma unroll
    for (int k = 0; k < NCH_; ++k) dec[k] = decay[bh * NCH_ + k];

    float acc16[16] = {};
    float wgt = 1.f;
    for (int cp = c - 1; cp >= 0; --cp) {
        const float* src = Sbuf + bhbase + (size_t)cp * 4096;
#pragma unroll
        for (int i = 0; i < 16; ++i) acc16[i] += wgt * src[i * 256 + tid];
        wgt *= dec[cp];
    }
#pragma unroll
    for (int i = 0; i < 16; ++i) Sm[i * 4 + wid][lane] = acc16[i];

    const size_t base = bhbase + (size_t)c * 4096;
    for (int r = 0; r < 64; r += 4) {
        int pp = r + wid;
        Cm[pp][lane] = Ctil[base + pp * 64 + lane];
    }
    __syncthreads();
    const int t4 = (tid & 15) * 4;
    const int r4 = (tid >> 4) * 4;
    float acc[4][4] = {};
    for (int ng = 0; ng < 64; ng += 4) {
        float4 cf[4], sf[4];
#pragma unroll
        for (int ii = 0; ii < 4; ++ii) cf[ii] = *(const float4*)&Cm[r4 + ii][ng];
#pragma unroll
        for (int pp = 0; pp < 4; ++pp) sf[pp] = *(const float4*)&Sm[t4 + pp][ng];
#pragma unroll
        for (int ii = 0; ii < 4; ++ii)
#pragma unroll
            for (int pp = 0; pp < 4; ++pp)
                acc[ii][pp] += cf[ii].x * sf[pp].x + cf[ii].y * sf[pp].y +
                               cf[ii].z * sf[pp].z + cf[ii].w * sf[pp].w;
    }
#pragma unroll
    for (int ii = 0; ii < 4; ++ii) {
        float* dst = &y[(size_t)(b * L_LEN + l0 + r4 + ii) * DIN_ + h * P_ + t4];
        float4 v = *(const float4*)dst;
        v.x += acc[ii][0]; v.y += acc[ii][1]; v.z += acc[ii][2]; v.w += acc[ii][3];
        *(float4*)dst = v;
    }
}

// y = rmsnorm(y * silu(z)) * norm_w   (in place)
__global__ void k_gatenorm(const float* __restrict__ zx, const float* __restrict__ nw,
                           float* __restrict__ y) {
    __shared__ float sred[4];
    int bl = blockIdx.x;
    float* yr = y + (size_t)bl * DIN_;
    const float* zr = zx + (size_t)bl * DPROJ_;
    int t = threadIdx.x;
    float g0 = yr[t] * siluf(zr[t]);
    float g1 = yr[t + 256] * siluf(zr[t + 256]);
    float ss = g0 * g0 + g1 * g1;
#pragma unroll
    for (int o = 32; o; o >>= 1) ss += __shfl_xor(ss, o, 64);
    if ((t & 63) == 0) sred[t >> 6] = ss;
    __syncthreads();
    ss = sred[0] + sred[1] + sred[2] + sred[3];
    float scale = rsqrtf(ss * (1.f / DIN_) + EPS_);
    yr[t] = g0 * scale * nw[t];
    yr[t + 256] = g1 * scale * nw[t + 256];
}

__global__ void k_pool1(const float* __restrict__ x, float* __restrict__ psum,
                        float* __restrict__ pmax) {
    int b = blockIdx.y, ch = blockIdx.x, d = threadIdx.x;
    const float* xb = x + ((size_t)(b * L_LEN) + ch * 64) * D_ + d;
    float s = 0.f, m = -INFINITY;
    for (int l = 0; l < 64; ++l) {
        float v = xb[(size_t)l * D_];
        s += v;
        m = fmaxf(m, v);
    }
    psum[(b * 16 + ch) * D_ + d] = s;
    pmax[(b * 16 + ch) * D_ + d] = m;
}

__global__ void k_poolhead(const float* __restrict__ psum, const float* __restrict__ pmax,
                           const float* __restrict__ pw, const float* __restrict__ pb,
                           const float* __restrict__ c1w, const float* __restrict__ c1b,
                           const float* __restrict__ c2w, const float* __restrict__ c2b,
                           float* __restrict__ out) {
    __shared__ float sp[256], s1[256], s2[128];
    int b = blockIdx.x, t = threadIdx.x;
    float s = 0.f, m = -INFINITY;
    for (int ch = 0; ch < 16; ++ch) {
        s += psum[(b * 16 + ch) * D_ + t];
        m = fmaxf(m, pmax[(b * 16 + ch) * D_ + t]);
    }
    sp[t] = (s * (1.f / L_LEN) + m) * 0.5f;
    __syncthreads();
    float acc = pb[t];
    for (int d = 0; d < 256; ++d) acc += sp[d] * pw[t * 256 + d];
    s1[t] = geluf(acc);
    __syncthreads();
    if (t < 128) {
        float a = c1b[t];
        for (int d = 0; d < 256; ++d) a += s1[d] * c1w[t * 256 + d];
        s2[t] = geluf(a);
    }
    __syncthreads();
    if (t < 2) {
        float a = c2b[t];
        for (int d = 0; d < 128; ++d) a += s2[d] * c2w[t * 128 + d];
        out[b * NC_ + t] = a;
    }
}

extern "C" void kernel_launch(void* const* d_in, const int* in_sizes, int n_in,
                              void* d_out, int out_size, void* d_ws, size_t ws_size,
                              hipStream_t stream) {
    const int* ids    = (const int*)d_in[0];
    const float* emb  = (const float*)d_in[1];
    const float* pos  = (const float*)d_in[2];
    const float* Wins = (const float*)d_in[3];
    const float* cw   = (const float*)d_in[4];
    const float* cb   = (const float*)d_in[5];
    const float* dtb  = (const float*)d_in[6];
    const float* Alog = (const float*)d_in[7];
    const float* Dpar = (const float*)d_in[8];
    const float* nw   = (const float*)d_in[9];
    const float* Wout = (const float*)d_in[10];
    const float* pw   = (const float*)d_in[11];
    const float* pb   = (const float*)d_in[12];
    const float* c1w  = (const float*)d_in[13];
    const float* c1b  = (const float*)d_in[14];
    const float* c2w  = (const float*)d_in[15];
    const float* c2b  = (const float*)d_in[16];
    float* out = (float*)d_out;

    const int NWIN = NL_ * DPROJ_ * D_;   // 1187840
    const int NWOUT = NL_ * D_ * DIN_;    // 524288

    float* ws = (float*)d_ws;
    float* x      = ws;                 // 524288
    float* zx     = x + 524288;         // 2375680
    float* y      = zx + 2375680;       // 1048576
    float* Sbuf   = y + 1048576;        // 1048576
    float* Ctil   = Sbuf + 1048576;     // 1048576
    float* decay  = Ctil + 1048576;     // 256
    float* psum   = decay + 256;        // 8192
    float* pmax   = psum + 8192;        // 8192
    unsigned short* winh = (unsigned short*)(pmax + 8192);
    unsigned short* winl = winh + NWIN;
    unsigned short* woh  = winl + NWIN;
    unsigned short* wol  = woh + NWOUT;

    k_w2bf<<<(NWIN + 255) / 256, 256, 0, stream>>>(Wins, winh, winl, NWIN);
    k_w2bf<<<(NWOUT + 255) / 256, 256, 0, stream>>>(Wout, woh, wol, NWOUT);
    k_embed<<<2048, 256, 0, stream>>>(ids, emb, pos, x, 524288);
    for (int i = 0; i < NL_; ++i) {
        size_t wo_in = (size_t)i * DPROJ_ * D_;
        size_t wo_out = (size_t)i * D_ * DIN_;
        gemm_bf3<false><<<dim3(19, 16, 1), 256, 0, stream>>>(
            x, winh + wo_in, winl + wo_in, zx, 2048, DPROJ_, D_, D_);
        k_ssmA<<<dim3(NCH_, 16), 256, 0, stream>>>(
            zx, cw + (size_t)i * CONVDIM_ * 4, cb + (size_t)i * CONVDIM_,
            dtb + i * H_, Alog + i * H_, Dpar + i * H_, Sbuf, decay, Ctil, y);
        k_inter<<<dim3(NCH_ - 1, 16), 256, 0, stream>>>(Sbuf, Ctil, decay, y);
        k_gatenorm<<<2048, 256, 0, stream>>>(zx, nw + (size_t)i * DIN_, y);
        gemm_bf3<true><<<dim3(4, 16, 4), 256, 0, stream>>>(
            y, woh + wo_out, wol + wo_out, x, 2048, D_, DIN_, 128);
    }
    k_pool1<<<dim3(16, 2), 256, 0, stream>>>(x, psum, pmax);
    k_poolhead<<<2, 256, 0, stream>>>(psum, pmax, pw, pb, c1w, c1b, c2w, c2b, out);
}